// Round 10
// baseline (199.377 us; speedup 1.0000x reference)
//
#include <hip/hip_runtime.h>
#include <hip/hip_bf16.h>
#include <stdint.h>

// Problem constants
constexpr int BB = 4;
constexpr int SS = 2048;
constexpr int DIN = 1024;
constexpr int HH = 16;
constexpr int DH = 64;
constexpr int NOUT = 4096;          // 4 * 1024 (Q|K|V|R)
constexpr int MROWS = BB * SS;      // 8192

typedef __attribute__((ext_vector_type(8))) short bf16x8;
typedef __attribute__((ext_vector_type(8))) unsigned short u16x8;
typedef __attribute__((ext_vector_type(4))) unsigned short u16x4;
typedef __attribute__((ext_vector_type(4))) float f32x4;

__device__ __forceinline__ unsigned short f2bf(float f) {
  unsigned int x = __float_as_uint(f);
  unsigned int r = (x + 0x7fffu + ((x >> 16) & 1u)) >> 16;
  return (unsigned short)r;
}
__device__ __forceinline__ float bf2f(unsigned short u) {
  return __uint_as_float(((unsigned int)u) << 16);
}

__device__ __forceinline__ void gload16(const void* g, void* l) {
  typedef __attribute__((address_space(1))) void gvoid;
  typedef __attribute__((address_space(3))) void lvoid;
  __builtin_amdgcn_global_load_lds((gvoid*)(uintptr_t)g, (lvoid*)l, 16, 0, 0);
}

// ---------------- fp32 -> bf16 conversions ----------------
__global__ __launch_bounds__(256) void convert_x(const float* __restrict__ src,
                                                 unsigned short* __restrict__ dst) {
  int i = (blockIdx.x * 256 + threadIdx.x) * 8;  // n = 8388608 exactly covered
  f32x4 a = *(const f32x4*)(src + i);
  f32x4 b = *(const f32x4*)(src + i + 4);
  u16x8 o;
  o[0] = f2bf(a[0]); o[1] = f2bf(a[1]); o[2] = f2bf(a[2]); o[3] = f2bf(a[3]);
  o[4] = f2bf(b[0]); o[5] = f2bf(b[1]); o[6] = f2bf(b[2]); o[7] = f2bf(b[3]);
  *(u16x8*)(dst + i) = o;
}

__global__ __launch_bounds__(256) void convert_w(const float* __restrict__ Wq,
                                                 const float* __restrict__ Wk,
                                                 const float* __restrict__ Wv,
                                                 const float* __restrict__ Wr,
                                                 unsigned short* __restrict__ dst) {
  int i = (blockIdx.x * 256 + threadIdx.x) * 8;   // 0 .. 4M
  int seg = i >> 20;                              // each W: 2^20 elems
  const float* src = (seg == 0) ? Wq : (seg == 1) ? Wk : (seg == 2) ? Wv : Wr;
  // fold 1/sqrt(64) AND log2(e) into Wq: scores come out in log2 domain
  float scale = (seg == 0) ? 0.125f * 1.44269504088896f : 1.0f;
  int j = i & 1048575;
  f32x4 a = *(const f32x4*)(src + j);
  f32x4 b = *(const f32x4*)(src + j + 4);
  u16x8 o;
  o[0] = f2bf(a[0] * scale); o[1] = f2bf(a[1] * scale);
  o[2] = f2bf(a[2] * scale); o[3] = f2bf(a[3] * scale);
  o[4] = f2bf(b[0] * scale); o[5] = f2bf(b[1] * scale);
  o[6] = f2bf(b[2] * scale); o[7] = f2bf(b[3] * scale);
  *(u16x8*)(dst + i) = o;
}

// ---------------- QKVR GEMM: Y[8192][4096] = X[8192][1024] @ W[4096][1024]^T ----------------
// 128x128 tile, BK=64, double-buffered XOR-swizzled LDS, counted vmcnt(8) pipeline
// (T3-minimum + T4: stage(t+2) issued under MFMA of tile t; never drain to 0 in-loop).
constexpr int GBM = 128, GBN = 128, GBK = 64;

__global__ __launch_bounds__(256) void gemm_qkvr(const unsigned short* __restrict__ X,
                                                 const unsigned short* __restrict__ Wt,
                                                 unsigned short* __restrict__ Y) {
  const int K = DIN;            // 1024, 16 K-tiles of 64
  const int nbn = NOUT / GBN;   // 32
  // XCD-chunked bijective swizzle (2048 % 8 == 0)
  int bid = blockIdx.x;
  int idx = (bid & 7) * 256 + (bid >> 3);
  int bm = idx / nbn, bn = idx % nbn;
  int m0 = bm * GBM, n0 = bn * GBN;
  int t = threadIdx.x;
  int w = t >> 6, l = t & 63;
  int lg = l >> 4, ll = l & 15;
  int wm = (w >> 1) * 64, wn = (w & 1) * 64;

  __shared__ unsigned short As[2][GBM * GBK];  // [128][64] swizzled, 16 KB x2
  __shared__ unsigned short Bs[2][GBN * GBK];  // rows = n

  f32x4 acc[4][4];
#pragma unroll
  for (int i = 0; i < 4; i++)
#pragma unroll
    for (int j = 0; j < 4; j++) acc[i][j] = (f32x4)0.0f;

  // staging: call c covers rows [c*32, c*32+32); wave w owns rows c*32+w*8..+7.
  // lane l -> row +(l>>3), phys 16B-slot l&7; pre-swizzled global col = (slot ^ (row&7)).
  int grow = t >> 3;   // w*8 + (l>>3), 0..31
  int gslot = t & 7;

  auto stage = [&](int kt, int bi) {
    int k0 = kt * GBK;
#pragma unroll
    for (int c = 0; c < 4; ++c) {
      int row = c * 32 + grow;
      int col = (gslot ^ (row & 7)) * 8;
      gload16(X + (size_t)(m0 + row) * K + k0 + col, &As[bi][c * 2048 + w * 512]);
      gload16(Wt + (size_t)(n0 + row) * K + k0 + col, &Bs[bi][c * 2048 + w * 512]);
    }
  };

  // prologue: fill both buffers; retire tile 0, keep tile 1 in flight (8 outstanding)
  stage(0, 0);
  stage(1, 1);
  asm volatile("s_waitcnt vmcnt(8)" ::: "memory");
  __builtin_amdgcn_s_barrier();
  __builtin_amdgcn_sched_barrier(0);

  for (int kt = 0; kt < 16; ++kt) {
    int cur = kt & 1;
    // read ALL fragments of this K-tile into registers (frees LDS for overwrite)
    bf16x8 af[4][2], bfr[4][2];
#pragma unroll
    for (int mt = 0; mt < 4; ++mt)
#pragma unroll
      for (int kk = 0; kk < 2; ++kk)
        af[mt][kk] = *(const bf16x8*)&As[cur][(wm + mt * 16 + ll) * GBK +
                                             ((kk * 4 + lg) ^ (ll & 7)) * 8];
#pragma unroll
    for (int nt = 0; nt < 4; ++nt)
#pragma unroll
      for (int kk = 0; kk < 2; ++kk)
        bfr[nt][kk] = *(const bf16x8*)&Bs[cur][(wn + nt * 16 + ll) * GBK +
                                              ((kk * 4 + lg) ^ (ll & 7)) * 8];
    asm volatile("s_waitcnt lgkmcnt(0)" ::: "memory");
    __builtin_amdgcn_s_barrier();          // all waves done reading buf[cur]
    __builtin_amdgcn_sched_barrier(0);

    stage((kt + 2) & 15, cur);             // overwrite buf[cur] under the MFMAs

    __builtin_amdgcn_s_setprio(1);
#pragma unroll
    for (int mt = 0; mt < 4; ++mt)
#pragma unroll
      for (int nt = 0; nt < 4; ++nt)
#pragma unroll
        for (int kk = 0; kk < 2; ++kk)
          acc[mt][nt] = __builtin_amdgcn_mfma_f32_16x16x32_bf16(af[mt][kk], bfr[nt][kk],
                                                                acc[mt][nt], 0, 0, 0);
    __builtin_amdgcn_s_setprio(0);

    asm volatile("s_waitcnt vmcnt(8)" ::: "memory");  // retire stage(kt+1): buf[cur^1] ready
    __builtin_amdgcn_s_barrier();
    __builtin_amdgcn_sched_barrier(0);
  }
  asm volatile("s_waitcnt vmcnt(0)" ::: "memory");  // drain tail stages before endpgm

  // epilogue: C/D mapping col = lane&15 (n), row = (lane>>4)*4 + r (m)
#pragma unroll
  for (int mt = 0; mt < 4; ++mt)
#pragma unroll
    for (int nt = 0; nt < 4; ++nt) {
      int n = n0 + wn + nt * 16 + ll;
#pragma unroll
      for (int r = 0; r < 4; ++r) {
        int m = m0 + wm + mt * 16 + lg * 4 + r;
        Y[(size_t)m * NOUT + n] = f2bf(acc[mt][nt][r]);
      }
    }
}

// ---------------- V transpose: (B,S,H,64) slice of qkvr -> Vt[(b*H+h)*64 + d][S] ----------------
__global__ __launch_bounds__(256) void transpose_v(const unsigned short* __restrict__ qkvr,
                                                   unsigned short* __restrict__ vt) {
  int bh = blockIdx.x >> 5;   // 0..63
  int st = blockIdx.x & 31;   // s-tile of 64
  int b = bh >> 4, h = bh & 15;
  __shared__ unsigned short tile[64][72];
  int t = threadIdx.x;
#pragma unroll
  for (int c = 0; c < 2; ++c) {
    int chunk = t + c * 256;
    int row = chunk >> 3;        // s 0..63
    int col = (chunk & 7) * 8;   // d
    u16x8 v = *(const u16x8*)(qkvr + (size_t)(b * SS + st * 64 + row) * NOUT + 2048 + h * DH + col);
    *(u16x8*)&tile[row][col] = v;
  }
  __syncthreads();
  int d = t >> 2;
  int s0 = (t & 3) * 16;
  u16x8 o0, o1;
#pragma unroll
  for (int i = 0; i < 8; ++i) o0[i] = tile[s0 + i][d];
#pragma unroll
  for (int i = 0; i < 8; ++i) o1[i] = tile[s0 + 8 + i][d];
  size_t orow = (size_t)(bh * DH + d) * SS + st * 64 + s0;
  *(u16x8*)(vt + orow) = o0;
  *(u16x8*)(vt + orow + 8) = o1;
}

// ---------------- Flash attention ----------------
// block: one (b,h), 256 q-rows; 8 waves x 32 rows. KV tiles of 64, double-buffered,
// counted vmcnt, XOR-swizzled K/V LDS. STATIC softmax (log2e folded into Wq).
// SWAPPED QK^T -> P lane-local per q-row; P via per-wave LDS P^T (b64 write / b128 read).
// Grid 512 = 64 bh x 8 qt, XCD-chunked swizzle; LDS 64KB -> exactly 2 blocks/CU.
__global__ __launch_bounds__(512) void attention(const unsigned short* __restrict__ qkvr,
                                                 const unsigned short* __restrict__ vt,
                                                 unsigned short* __restrict__ attn) {
  int bid = blockIdx.x;                    // 512 blocks
  int idx = (bid & 7) * 64 + (bid >> 3);   // XCD-chunked bijective swizzle
  int qt = idx & 7;
  int bh = idx >> 3;
  int b = bh >> 4, h = bh & 15;
  int t = threadIdx.x, w = t >> 6, l = t & 63;
  int lg = l >> 4, ll = l & 15;

  __shared__ unsigned short Ks[2][4096];   // [64 k][64 d] x2, swizzled (16 KB)
  __shared__ unsigned short Vs[2][4096];   // Vt tile [64 d][64 s] x2, swizzled (16 KB)
  __shared__ unsigned short Ps[8][2048];   // per-wave P^T [32 q][64 k], swizzled (32 KB)

  const unsigned short* kbase = qkvr + (size_t)(b * SS) * NOUT + 1024 + h * DH;
  const unsigned short* vbase = vt + (size_t)(bh * DH) * SS;

  // Q fragments (B-operand: col q = ll, mfma-k (d) = kk*32 + lg*8 + 0..7)
  bf16x8 qb[2][2];
#pragma unroll
  for (int m = 0; m < 2; ++m) {
    int qrow = b * SS + qt * 256 + w * 32 + m * 16 + ll;
#pragma unroll
    for (int kk = 0; kk < 2; ++kk)
      qb[m][kk] = *(const bf16x8*)(qkvr + (size_t)qrow * NOUT + h * DH + kk * 32 + lg * 8);
  }

  f32x4 acc[2][4];
#pragma unroll
  for (int m = 0; m < 2; ++m)
#pragma unroll
    for (int i = 0; i < 4; i++) acc[m][i] = (f32x4)0.0f;
  float lsum[2] = {0.0f, 0.0f};  // per-lane partial denominator for q = m*16 + ll

  // staging (512 threads): lane t -> row = t>>3 (0..63), 16B slot = t&7,
  // pre-swizzled global col: slot ^ (row&7). LDS dest linear: wave base + lane*16.
  int grow = t >> 3;
  int gcol = ((t & 7) ^ (grow & 7)) * 8;

  auto stage = [&](int tile, int bi) {
    gload16(kbase + (size_t)(tile * 64 + grow) * NOUT + gcol, &Ks[bi][w * 512]);
    gload16(vbase + (size_t)grow * SS + tile * 64 + gcol, &Vs[bi][w * 512]);
  };

  stage(0, 0);

  for (int kt = 0; kt < 32; ++kt) {
    int bi = kt & 1;
    stage((kt + 1) & 31, bi ^ 1);  // kt=31 re-stages tile 0 (harmless) to keep vmcnt uniform
    asm volatile("s_waitcnt vmcnt(2)" ::: "memory");
    __builtin_amdgcn_s_barrier();
    __builtin_amdgcn_sched_barrier(0);

    // S'^T = K Q^T (log2 domain): s[m][nt][r] -> q = m*16+ll, k = nt*16+lg*4+r
    f32x4 s[2][4];
#pragma unroll
    for (int m = 0; m < 2; ++m)
#pragma unroll
      for (int nt = 0; nt < 4; nt++) s[m][nt] = (f32x4)0.0f;
    __builtin_amdgcn_s_setprio(1);
#pragma unroll
    for (int nt = 0; nt < 4; ++nt)
#pragma unroll
      for (int kk = 0; kk < 2; ++kk) {
        bf16x8 kb = *(const bf16x8*)&Ks[bi][(nt * 16 + ll) * 64 + ((kk * 4 + lg) ^ (ll & 7)) * 8];
        s[0][nt] = __builtin_amdgcn_mfma_f32_16x16x32_bf16(kb, qb[0][kk], s[0][nt], 0, 0, 0);
        s[1][nt] = __builtin_amdgcn_mfma_f32_16x16x32_bf16(kb, qb[1][kk], s[1][nt], 0, 0, 0);
      }
    __builtin_amdgcn_s_setprio(0);

    // P = exp2(S'); per-lane partial denominator (q = m*16+ll: lane-local row)
#pragma unroll
    for (int m = 0; m < 2; ++m) {
      float ps = 0.0f;
#pragma unroll
      for (int nt = 0; nt < 4; nt++)
#pragma unroll
        for (int r = 0; r < 4; r++) {
          float e;
          asm("v_exp_f32 %0, %1" : "=v"(e) : "v"(s[m][nt][r]));
          s[m][nt][r] = e;
          ps += e;
        }
      lsum[m] += ps;
    }

    // pack 4 consecutive k (nt*16+lg*4+0..3) -> b64 store into P^T row q=m*16+ll.
    // swizzle: 16B-slot (2nt + (lg>>1)) ^ (row&7), row&7 == ll&7; 8B half = lg&1.
#pragma unroll
    for (int m = 0; m < 2; ++m) {
      char* prow = (char*)&Ps[w][0] + (m * 16 + ll) * 128;
#pragma unroll
      for (int nt = 0; nt < 4; nt++) {
        unsigned sp0, sp1;
        asm("v_cvt_pk_bf16_f32 %0, %1, %2" : "=v"(sp0) : "v"(s[m][nt][0]), "v"(s[m][nt][1]));
        asm("v_cvt_pk_bf16_f32 %0, %1, %2" : "=v"(sp1) : "v"(s[m][nt][2]), "v"(s[m][nt][3]));
        uint2 pv; pv.x = sp0; pv.y = sp1;
        *(uint2*)(prow + ((2 * nt + (lg >> 1)) ^ (ll & 7)) * 16 + (lg & 1) * 8) = pv;
      }
    }

    // PV A-frags: row q = m*16+ll, k = kk*32+lg*8+0..7 -> slot (4kk+lg)^(ll&7)
    bf16x8 pa[2][2];
#pragma unroll
    for (int m = 0; m < 2; ++m)
#pragma unroll
      for (int kk = 0; kk < 2; ++kk)
        pa[m][kk] = *(const bf16x8*)((char*)&Ps[w][0] + (m * 16 + ll) * 128 +
                                     ((4 * kk + lg) ^ (ll & 7)) * 16);

    // PV: A = P (row=q), B = Vt tile [d][k] (k-contiguous)
    __builtin_amdgcn_s_setprio(1);
#pragma unroll
    for (int kk = 0; kk < 2; ++kk) {
#pragma unroll
      for (int dt = 0; dt < 4; ++dt) {
        bf16x8 vb = *(const bf16x8*)&Vs[bi][(dt * 16 + ll) * 64 + ((kk * 4 + lg) ^ (ll & 7)) * 8];
        acc[0][dt] = __builtin_amdgcn_mfma_f32_16x16x32_bf16(pa[0][kk], vb, acc[0][dt], 0, 0, 0);
        acc[1][dt] = __builtin_amdgcn_mfma_f32_16x16x32_bf16(pa[1][kk], vb, acc[1][dt], 0, 0, 0);
      }
    }
    __builtin_amdgcn_s_setprio(0);
    __builtin_amdgcn_s_barrier();
    __builtin_amdgcn_sched_barrier(0);
  }
  asm volatile("s_waitcnt vmcnt(0)" ::: "memory");  // drain dummy stage before endpgm

  // denominator: reduce across lg groups (k-partials), then redistribute to output rows
  float inv[2][4];
#pragma unroll
  for (int m = 0; m < 2; ++m) {
    float lr = lsum[m];
    lr += __shfl_xor(lr, 16);
    lr += __shfl_xor(lr, 32);   // lane x now holds full denom for q = m*16 + (x&15)
#pragma unroll
    for (int r = 0; r < 4; r++)
      inv[m][r] = 1.0f / __shfl(lr, lg * 4 + r);
  }
  // output: acc[m][dt][r] -> q = m*16 + lg*4 + r, d = dt*16 + ll
#pragma unroll
  for (int m = 0; m < 2; ++m)
#pragma unroll
    for (int r = 0; r < 4; r++) {
      int arow = b * SS + qt * 256 + w * 32 + m * 16 + lg * 4 + r;
#pragma unroll
      for (int dt = 0; dt < 4; dt++)
        attn[(size_t)arow * DIN + h * DH + dt * 16 + ll] = f2bf(acc[m][dt][r] * inv[m][r]);
    }
}

// ---------------- LayerNorm epilogue: out = LN(relu(attn + R)) ----------------
__global__ __launch_bounds__(256) void ln_epilogue(const unsigned short* __restrict__ attn,
                                                   const unsigned short* __restrict__ qkvr,
                                                   const float* __restrict__ gamma,
                                                   const float* __restrict__ beta,
                                                   float* __restrict__ out) {
  int row = blockIdx.x;
  int t = threadIdx.x;
  u16x4 av = *(const u16x4*)(attn + (size_t)row * DIN + t * 4);
  u16x4 rv = *(const u16x4*)(qkvr + (size_t)row * NOUT + 3072 + t * 4);
  float v[4];
  float s = 0.0f, s2 = 0.0f;
#pragma unroll
  for (int i = 0; i < 4; i++) {
    v[i] = fmaxf(bf2f(av[i]) + bf2f(rv[i]), 0.0f);
    s += v[i];
    s2 += v[i] * v[i];
  }
#pragma unroll
  for (int m = 1; m < 64; m <<= 1) {
    s += __shfl_xor(s, m);
    s2 += __shfl_xor(s2, m);
  }
  __shared__ float red[2][4];
  int w = t >> 6, l = t & 63;
  if (l == 0) { red[0][w] = s; red[1][w] = s2; }
  __syncthreads();
  s = red[0][0] + red[0][1] + red[0][2] + red[0][3];
  s2 = red[1][0] + red[1][1] + red[1][2] + red[1][3];
  float mu = s * (1.0f / 1024.0f);
  float var = s2 * (1.0f / 1024.0f) - mu * mu;
  float rstd = rsqrtf(var + 1e-5f);
  f32x4 g = *(const f32x4*)(gamma + t * 4);
  f32x4 be = *(const f32x4*)(beta + t * 4);
  f32x4 o;
#pragma unroll
  for (int i = 0; i < 4; i++) o[i] = (v[i] - mu) * rstd * g[i] + be[i];
  *(f32x4*)(out + (size_t)row * DIN + t * 4) = o;
}

extern "C" void kernel_launch(void* const* d_in, const int* in_sizes, int n_in,
                              void* d_out, int out_size, void* d_ws, size_t ws_size,
                              hipStream_t stream) {
  const float* x = (const float*)d_in[0];
  const float* Wq = (const float*)d_in[1];
  const float* Wk = (const float*)d_in[2];
  const float* Wv = (const float*)d_in[3];
  const float* Wr = (const float*)d_in[4];
  const float* gamma = (const float*)d_in[5];
  const float* beta = (const float*)d_in[6];
  float* out = (float*)d_out;

  char* ws = (char*)d_ws;
  unsigned short* x_bf = (unsigned short*)ws;                        // 16 MB
  unsigned short* w_bf = (unsigned short*)(ws + (16ull << 20));      // 8 MB
  unsigned short* qkvr = (unsigned short*)(ws + (24ull << 20));      // 64 MB
  unsigned short* vt   = (unsigned short*)(ws + (88ull << 20));      // 16 MB
  unsigned short* attn = (unsigned short*)(ws + (104ull << 20));     // 16 MB (total 120 MB)

  convert_x<<<4096, 256, 0, stream>>>(x, x_bf);
  convert_w<<<2048, 256, 0, stream>>>(Wq, Wk, Wv, Wr, w_bf);
  gemm_qkvr<<<(MROWS / GBM) * (NOUT / GBN), 256, 0, stream>>>(x_bf, w_bf, qkvr);
  transpose_v<<<2048, 256, 0, stream>>>(qkvr, vt);
  attention<<<512, 512, 0, stream>>>(qkvr, vt, attn);
  ln_epilogue<<<MROWS, 256, 0, stream>>>(attn, qkvr, gamma, beta, out);
}

// Round 12
// 191.431 us; speedup vs baseline: 1.0415x; 1.0415x over previous
//
#include <hip/hip_runtime.h>
#include <hip/hip_bf16.h>
#include <stdint.h>

// Problem constants
constexpr int BB = 4;
constexpr int SS = 2048;
constexpr int DIN = 1024;
constexpr int HH = 16;
constexpr int DH = 64;
constexpr int NOUT = 4096;          // 4 * 1024 (Q|K|V|R)
constexpr int MROWS = BB * SS;      // 8192

typedef __attribute__((ext_vector_type(8))) short bf16x8;
typedef __attribute__((ext_vector_type(8))) unsigned short u16x8;
typedef __attribute__((ext_vector_type(4))) unsigned short u16x4;
typedef __attribute__((ext_vector_type(4))) float f32x4;

__device__ __forceinline__ unsigned short f2bf(float f) {
  unsigned int x = __float_as_uint(f);
  unsigned int r = (x + 0x7fffu + ((x >> 16) & 1u)) >> 16;
  return (unsigned short)r;
}
__device__ __forceinline__ float bf2f(unsigned short u) {
  return __uint_as_float(((unsigned int)u) << 16);
}

__device__ __forceinline__ void gload16(const void* g, void* l) {
  typedef __attribute__((address_space(1))) void gvoid;
  typedef __attribute__((address_space(3))) void lvoid;
  __builtin_amdgcn_global_load_lds((gvoid*)(uintptr_t)g, (lvoid*)l, 16, 0, 0);
}

// ---------------- fp32 -> bf16 conversions ----------------
__global__ __launch_bounds__(256) void convert_x(const float* __restrict__ src,
                                                 unsigned short* __restrict__ dst) {
  int i = (blockIdx.x * 256 + threadIdx.x) * 8;  // n = 8388608 exactly covered
  f32x4 a = *(const f32x4*)(src + i);
  f32x4 b = *(const f32x4*)(src + i + 4);
  u16x8 o;
  o[0] = f2bf(a[0]); o[1] = f2bf(a[1]); o[2] = f2bf(a[2]); o[3] = f2bf(a[3]);
  o[4] = f2bf(b[0]); o[5] = f2bf(b[1]); o[6] = f2bf(b[2]); o[7] = f2bf(b[3]);
  *(u16x8*)(dst + i) = o;
}

__global__ __launch_bounds__(256) void convert_w(const float* __restrict__ Wq,
                                                 const float* __restrict__ Wk,
                                                 const float* __restrict__ Wv,
                                                 const float* __restrict__ Wr,
                                                 unsigned short* __restrict__ dst) {
  int i = (blockIdx.x * 256 + threadIdx.x) * 8;   // 0 .. 4M
  int seg = i >> 20;                              // each W: 2^20 elems
  const float* src = (seg == 0) ? Wq : (seg == 1) ? Wk : (seg == 2) ? Wv : Wr;
  // fold 1/sqrt(64) AND log2(e) into Wq: scores come out in log2 domain
  float scale = (seg == 0) ? 0.125f * 1.44269504088896f : 1.0f;
  int j = i & 1048575;
  f32x4 a = *(const f32x4*)(src + j);
  f32x4 b = *(const f32x4*)(src + j + 4);
  u16x8 o;
  o[0] = f2bf(a[0] * scale); o[1] = f2bf(a[1] * scale);
  o[2] = f2bf(a[2] * scale); o[3] = f2bf(a[3] * scale);
  o[4] = f2bf(b[0] * scale); o[5] = f2bf(b[1] * scale);
  o[6] = f2bf(b[2] * scale); o[7] = f2bf(b[3] * scale);
  *(u16x8*)(dst + i) = o;
}

// ---------------- QKVR GEMM: Y[8192][4096] = X[8192][1024] @ W[4096][1024]^T ----------------
// 128x128 tile, BK=64, double-buffered XOR-swizzled LDS, counted vmcnt(8) pipeline.
// MFMAs precede the barrier so the compiler's fine-grained lgkmcnt interleaves
// ds_read<->MFMA (no explicit drain before compute); stage(t+2) flies across the
// NEXT iteration's reads+MFMA; vmcnt never drains below 8 in-loop.
constexpr int GBM = 128, GBN = 128, GBK = 64;

__global__ __launch_bounds__(256) void gemm_qkvr(const unsigned short* __restrict__ X,
                                                 const unsigned short* __restrict__ Wt,
                                                 unsigned short* __restrict__ Y) {
  const int K = DIN;            // 1024, 16 K-tiles of 64
  const int nbn = NOUT / GBN;   // 32
  // XCD-chunked bijective swizzle (2048 % 8 == 0)
  int bid = blockIdx.x;
  int idx = (bid & 7) * 256 + (bid >> 3);
  int bm = idx / nbn, bn = idx % nbn;
  int m0 = bm * GBM, n0 = bn * GBN;
  int t = threadIdx.x;
  int w = t >> 6, l = t & 63;
  int lg = l >> 4, ll = l & 15;
  int wm = (w >> 1) * 64, wn = (w & 1) * 64;

  __shared__ unsigned short As[2][GBM * GBK];  // [128][64] swizzled, 16 KB x2
  __shared__ unsigned short Bs[2][GBN * GBK];  // rows = n

  f32x4 acc[4][4];
#pragma unroll
  for (int i = 0; i < 4; i++)
#pragma unroll
    for (int j = 0; j < 4; j++) acc[i][j] = (f32x4)0.0f;

  // staging: call c covers rows [c*32, c*32+32); wave w owns rows c*32+w*8..+7.
  // lane l -> row +(l>>3), phys 16B-slot l&7; pre-swizzled global col = (slot ^ (row&7)).
  int grow = t >> 3;   // w*8 + (l>>3), 0..31
  int gslot = t & 7;

  auto stage = [&](int kt, int bi) {
    int k0 = kt * GBK;
#pragma unroll
    for (int c = 0; c < 4; ++c) {
      int row = c * 32 + grow;
      int col = (gslot ^ (row & 7)) * 8;
      gload16(X + (size_t)(m0 + row) * K + k0 + col, &As[bi][c * 2048 + w * 512]);
      gload16(Wt + (size_t)(n0 + row) * K + k0 + col, &Bs[bi][c * 2048 + w * 512]);
    }
  };

  // prologue: fill both buffers; retire tile 0, keep tile 1 in flight (8 outstanding)
  stage(0, 0);
  stage(1, 1);
  asm volatile("s_waitcnt vmcnt(8)" ::: "memory");
  __builtin_amdgcn_s_barrier();

  for (int kt = 0; kt < 16; ++kt) {
    int cur = kt & 1;
    // reads + MFMAs: NO explicit waits between them — compiler emits fine-grained
    // lgkmcnt so the MFMA stream starts as soon as its first operands land.
    bf16x8 af[4][2], bfr[4][2];
#pragma unroll
    for (int mt = 0; mt < 4; ++mt)
#pragma unroll
      for (int kk = 0; kk < 2; ++kk) {
        af[mt][kk] = *(const bf16x8*)&As[cur][(wm + mt * 16 + ll) * GBK +
                                             ((kk * 4 + lg) ^ (ll & 7)) * 8];
        bfr[mt][kk] = *(const bf16x8*)&Bs[cur][(wn + mt * 16 + ll) * GBK +
                                              ((kk * 4 + lg) ^ (ll & 7)) * 8];
      }
    __builtin_amdgcn_s_setprio(1);
#pragma unroll
    for (int mt = 0; mt < 4; ++mt)
#pragma unroll
      for (int nt = 0; nt < 4; ++nt)
#pragma unroll
        for (int kk = 0; kk < 2; ++kk)
          acc[mt][nt] = __builtin_amdgcn_mfma_f32_16x16x32_bf16(af[mt][kk], bfr[nt][kk],
                                                                acc[mt][nt], 0, 0, 0);
    __builtin_amdgcn_s_setprio(0);

    asm volatile("s_waitcnt lgkmcnt(0)" ::: "memory");  // all reads of buf[cur] done
    __builtin_amdgcn_s_barrier();

    stage((kt + 2) & 15, cur);             // overwrite buf[cur]; flies across next iter

    asm volatile("s_waitcnt vmcnt(8)" ::: "memory");  // retire stage(kt+1): buf[cur^1] ready
    __builtin_amdgcn_s_barrier();
  }
  asm volatile("s_waitcnt vmcnt(0)" ::: "memory");  // drain tail stages before endpgm

  // epilogue: C/D mapping col = lane&15 (n), row = (lane>>4)*4 + r (m)
#pragma unroll
  for (int mt = 0; mt < 4; ++mt)
#pragma unroll
    for (int nt = 0; nt < 4; ++nt) {
      int n = n0 + wn + nt * 16 + ll;
#pragma unroll
      for (int r = 0; r < 4; ++r) {
        int m = m0 + wm + mt * 16 + lg * 4 + r;
        Y[(size_t)m * NOUT + n] = f2bf(acc[mt][nt][r]);
      }
    }
}

// ---------------- V transpose: (B,S,H,64) slice of qkvr -> Vt[(b*H+h)*64 + d][S] ----------------
__global__ __launch_bounds__(256) void transpose_v(const unsigned short* __restrict__ qkvr,
                                                   unsigned short* __restrict__ vt) {
  int bh = blockIdx.x >> 5;   // 0..63
  int st = blockIdx.x & 31;   // s-tile of 64
  int b = bh >> 4, h = bh & 15;
  __shared__ unsigned short tile[64][72];
  int t = threadIdx.x;
#pragma unroll
  for (int c = 0; c < 2; ++c) {
    int chunk = t + c * 256;
    int row = chunk >> 3;        // s 0..63
    int col = (chunk & 7) * 8;   // d
    u16x8 v = *(const u16x8*)(qkvr + (size_t)(b * SS + st * 64 + row) * NOUT + 2048 + h * DH + col);
    *(u16x8*)&tile[row][col] = v;
  }
  __syncthreads();
  int d = t >> 2;
  int s0 = (t & 3) * 16;
  u16x8 o0, o1;
#pragma unroll
  for (int i = 0; i < 8; ++i) o0[i] = tile[s0 + i][d];
#pragma unroll
  for (int i = 0; i < 8; ++i) o1[i] = tile[s0 + 8 + i][d];
  size_t orow = (size_t)(bh * DH + d) * SS + st * 64 + s0;
  *(u16x8*)(vt + orow) = o0;
  *(u16x8*)(vt + orow + 8) = o1;
}

// ---------------- Flash attention ----------------
// block: one (b,h), 256 q-rows; 8 waves x 32 rows. KV tiles of 64, double-buffered,
// counted vmcnt, XOR-swizzled K/V LDS. STATIC softmax (log2e folded into Wq).
// SWAPPED QK^T -> P lane-local per q-row; P via per-wave LDS P^T (b64 write / b128 read).
// DENOMINATOR VIA MFMA: extra PV-style mfma against an all-ones B fragment; its C
// layout (q = m*16 + lg*4 + r per lane) matches the output store exactly -> no
// cross-lane reduce, no per-element VALU sum.
__global__ __launch_bounds__(512) void attention(const unsigned short* __restrict__ qkvr,
                                                 const unsigned short* __restrict__ vt,
                                                 unsigned short* __restrict__ attn) {
  int bid = blockIdx.x;                    // 512 blocks
  int idx = (bid & 7) * 64 + (bid >> 3);   // XCD-chunked bijective swizzle
  int qt = idx & 7;
  int bh = idx >> 3;
  int b = bh >> 4, h = bh & 15;
  int t = threadIdx.x, w = t >> 6, l = t & 63;
  int lg = l >> 4, ll = l & 15;

  __shared__ unsigned short Ks[2][4096];   // [64 k][64 d] x2, swizzled (16 KB)
  __shared__ unsigned short Vs[2][4096];   // Vt tile [64 d][64 s] x2, swizzled (16 KB)
  __shared__ unsigned short Ps[8][2048];   // per-wave P^T [32 q][64 k], swizzled (32 KB)

  const unsigned short* kbase = qkvr + (size_t)(b * SS) * NOUT + 1024 + h * DH;
  const unsigned short* vbase = vt + (size_t)(bh * DH) * SS;

  // Q fragments (B-operand: col q = ll, mfma-k (d) = kk*32 + lg*8 + 0..7)
  bf16x8 qb[2][2];
#pragma unroll
  for (int m = 0; m < 2; ++m) {
    int qrow = b * SS + qt * 256 + w * 32 + m * 16 + ll;
#pragma unroll
    for (int kk = 0; kk < 2; ++kk)
      qb[m][kk] = *(const bf16x8*)(qkvr + (size_t)qrow * NOUT + h * DH + kk * 32 + lg * 8);
  }

  bf16x8 ones;
#pragma unroll
  for (int i = 0; i < 8; i++) ones[i] = (short)0x3F80;  // bf16 1.0

  f32x4 acc[2][4];
  f32x4 dacc[2];                 // denominator accumulator (mfma C layout)
#pragma unroll
  for (int m = 0; m < 2; ++m) {
    dacc[m] = (f32x4)0.0f;
#pragma unroll
    for (int i = 0; i < 4; i++) acc[m][i] = (f32x4)0.0f;
  }

  // staging (512 threads): lane t -> row = t>>3 (0..63), 16B slot = t&7,
  // pre-swizzled global col: slot ^ (row&7). LDS dest linear: wave base + lane*16.
  int grow = t >> 3;
  int gcol = ((t & 7) ^ (grow & 7)) * 8;

  auto stage = [&](int tile, int bi) {
    gload16(kbase + (size_t)(tile * 64 + grow) * NOUT + gcol, &Ks[bi][w * 512]);
    gload16(vbase + (size_t)grow * SS + tile * 64 + gcol, &Vs[bi][w * 512]);
  };

  stage(0, 0);

  for (int kt = 0; kt < 32; ++kt) {
    int bi = kt & 1;
    stage((kt + 1) & 31, bi ^ 1);  // kt=31 re-stages tile 0 (harmless) to keep vmcnt uniform
    asm volatile("s_waitcnt vmcnt(2)" ::: "memory");
    __builtin_amdgcn_s_barrier();
    __builtin_amdgcn_sched_barrier(0);

    // S'^T = K Q^T (log2 domain): s[m][nt][r] -> q = m*16+ll, k = nt*16+lg*4+r
    f32x4 s[2][4];
#pragma unroll
    for (int m = 0; m < 2; ++m)
#pragma unroll
      for (int nt = 0; nt < 4; nt++) s[m][nt] = (f32x4)0.0f;
    __builtin_amdgcn_s_setprio(1);
#pragma unroll
    for (int nt = 0; nt < 4; ++nt)
#pragma unroll
      for (int kk = 0; kk < 2; ++kk) {
        bf16x8 kb = *(const bf16x8*)&Ks[bi][(nt * 16 + ll) * 64 + ((kk * 4 + lg) ^ (ll & 7)) * 8];
        s[0][nt] = __builtin_amdgcn_mfma_f32_16x16x32_bf16(kb, qb[0][kk], s[0][nt], 0, 0, 0);
        s[1][nt] = __builtin_amdgcn_mfma_f32_16x16x32_bf16(kb, qb[1][kk], s[1][nt], 0, 0, 0);
      }
    __builtin_amdgcn_s_setprio(0);

    // P = exp2(S') (no max, no rescale, no VALU sum — denom comes from MFMA below)
#pragma unroll
    for (int m = 0; m < 2; ++m)
#pragma unroll
      for (int nt = 0; nt < 4; nt++)
#pragma unroll
        for (int r = 0; r < 4; r++) {
          float e;
          asm("v_exp_f32 %0, %1" : "=v"(e) : "v"(s[m][nt][r]));
          s[m][nt][r] = e;
        }

    // pack 4 consecutive k (nt*16+lg*4+0..3) -> b64 store into P^T row q=m*16+ll.
    // swizzle: 16B-slot (2nt + (lg>>1)) ^ (row&7), row&7 == ll&7; 8B half = lg&1.
#pragma unroll
    for (int m = 0; m < 2; ++m) {
      char* prow = (char*)&Ps[w][0] + (m * 16 + ll) * 128;
#pragma unroll
      for (int nt = 0; nt < 4; nt++) {
        unsigned sp0, sp1;
        asm("v_cvt_pk_bf16_f32 %0, %1, %2" : "=v"(sp0) : "v"(s[m][nt][0]), "v"(s[m][nt][1]));
        asm("v_cvt_pk_bf16_f32 %0, %1, %2" : "=v"(sp1) : "v"(s[m][nt][2]), "v"(s[m][nt][3]));
        uint2 pv; pv.x = sp0; pv.y = sp1;
        *(uint2*)(prow + ((2 * nt + (lg >> 1)) ^ (ll & 7)) * 16 + (lg & 1) * 8) = pv;
      }
    }

    // PV A-frags: row q = m*16+ll, k = kk*32+lg*8+0..7 -> slot (4kk+lg)^(ll&7)
    bf16x8 pa[2][2];
#pragma unroll
    for (int m = 0; m < 2; ++m)
#pragma unroll
      for (int kk = 0; kk < 2; ++kk)
        pa[m][kk] = *(const bf16x8*)((char*)&Ps[w][0] + (m * 16 + ll) * 128 +
                                     ((4 * kk + lg) ^ (ll & 7)) * 16);

    // PV: A = P (row=q), B = Vt tile [d][k] (k-contiguous); + denominator mfma (B=ones)
    __builtin_amdgcn_s_setprio(1);
#pragma unroll
    for (int kk = 0; kk < 2; ++kk) {
#pragma unroll
      for (int dt = 0; dt < 4; ++dt) {
        bf16x8 vb = *(const bf16x8*)&Vs[bi][(dt * 16 + ll) * 64 + ((kk * 4 + lg) ^ (ll & 7)) * 8];
        acc[0][dt] = __builtin_amdgcn_mfma_f32_16x16x32_bf16(pa[0][kk], vb, acc[0][dt], 0, 0, 0);
        acc[1][dt] = __builtin_amdgcn_mfma_f32_16x16x32_bf16(pa[1][kk], vb, acc[1][dt], 0, 0, 0);
      }
      dacc[0] = __builtin_amdgcn_mfma_f32_16x16x32_bf16(pa[0][kk], ones, dacc[0], 0, 0, 0);
      dacc[1] = __builtin_amdgcn_mfma_f32_16x16x32_bf16(pa[1][kk], ones, dacc[1], 0, 0, 0);
    }
    __builtin_amdgcn_s_setprio(0);
    __builtin_amdgcn_s_barrier();
    __builtin_amdgcn_sched_barrier(0);
  }
  asm volatile("s_waitcnt vmcnt(0)" ::: "memory");  // drain dummy stage before endpgm

  // output: acc[m][dt][r] -> q = m*16 + lg*4 + r, d = dt*16 + ll.
  // dacc[m][r] holds the full denominator for exactly that q — no shuffles needed.
#pragma unroll
  for (int m = 0; m < 2; ++m)
#pragma unroll
    for (int r = 0; r < 4; r++) {
      float inv = 1.0f / dacc[m][r];
      int arow = b * SS + qt * 256 + w * 32 + m * 16 + lg * 4 + r;
#pragma unroll
      for (int dt = 0; dt < 4; dt++)
        attn[(size_t)arow * DIN + h * DH + dt * 16 + ll] = f2bf(acc[m][dt][r] * inv);
    }
}

// ---------------- LayerNorm epilogue: out = LN(relu(attn + R)) ----------------
__global__ __launch_bounds__(256) void ln_epilogue(const unsigned short* __restrict__ attn,
                                                   const unsigned short* __restrict__ qkvr,
                                                   const float* __restrict__ gamma,
                                                   const float* __restrict__ beta,
                                                   float* __restrict__ out) {
  int row = blockIdx.x;
  int t = threadIdx.x;
  u16x4 av = *(const u16x4*)(attn + (size_t)row * DIN + t * 4);
  u16x4 rv = *(const u16x4*)(qkvr + (size_t)row * NOUT + 3072 + t * 4);
  float v[4];
  float s = 0.0f, s2 = 0.0f;
#pragma unroll
  for (int i = 0; i < 4; i++) {
    v[i] = fmaxf(bf2f(av[i]) + bf2f(rv[i]), 0.0f);
    s += v[i];
    s2 += v[i] * v[i];
  }
#pragma unroll
  for (int m = 1; m < 64; m <<= 1) {
    s += __shfl_xor(s, m);
    s2 += __shfl_xor(s2, m);
  }
  __shared__ float red[2][4];
  int w = t >> 6, l = t & 63;
  if (l == 0) { red[0][w] = s; red[1][w] = s2; }
  __syncthreads();
  s = red[0][0] + red[0][1] + red[0][2] + red[0][3];
  s2 = red[1][0] + red[1][1] + red[1][2] + red[1][3];
  float mu = s * (1.0f / 1024.0f);
  float var = s2 * (1.0f / 1024.0f) - mu * mu;
  float rstd = rsqrtf(var + 1e-5f);
  f32x4 g = *(const f32x4*)(gamma + t * 4);
  f32x4 be = *(const f32x4*)(beta + t * 4);
  f32x4 o;
#pragma unroll
  for (int i = 0; i < 4; i++) o[i] = (v[i] - mu) * rstd * g[i] + be[i];
  *(f32x4*)(out + (size_t)row * DIN + t * 4) = o;
}

extern "C" void kernel_launch(void* const* d_in, const int* in_sizes, int n_in,
                              void* d_out, int out_size, void* d_ws, size_t ws_size,
                              hipStream_t stream) {
  const float* x = (const float*)d_in[0];
  const float* Wq = (const float*)d_in[1];
  const float* Wk = (const float*)d_in[2];
  const float* Wv = (const float*)d_in[3];
  const float* Wr = (const float*)d_in[4];
  const float* gamma = (const float*)d_in[5];
  const float* beta = (const float*)d_in[6];
  float* out = (float*)d_out;

  char* ws = (char*)d_ws;
  unsigned short* x_bf = (unsigned short*)ws;                        // 16 MB
  unsigned short* w_bf = (unsigned short*)(ws + (16ull << 20));      // 8 MB
  unsigned short* qkvr = (unsigned short*)(ws + (24ull << 20));      // 64 MB
  unsigned short* vt   = (unsigned short*)(ws + (88ull << 20));      // 16 MB
  unsigned short* attn = (unsigned short*)(ws + (104ull << 20));     // 16 MB (total 120 MB)

  convert_x<<<4096, 256, 0, stream>>>(x, x_bf);
  convert_w<<<2048, 256, 0, stream>>>(Wq, Wk, Wv, Wr, w_bf);
  gemm_qkvr<<<(MROWS / GBM) * (NOUT / GBN), 256, 0, stream>>>(x_bf, w_bf, qkvr);
  transpose_v<<<2048, 256, 0, stream>>>(qkvr, vt);
  attention<<<512, 512, 0, stream>>>(qkvr, vt, attn);
  ln_epilogue<<<MROWS, 256, 0, stream>>>(attn, qkvr, gamma, beta, out);
}

// Round 13
// 184.171 us; speedup vs baseline: 1.0826x; 1.0394x over previous
//
#include <hip/hip_runtime.h>
#include <hip/hip_bf16.h>
#include <stdint.h>

// Problem constants
constexpr int BB = 4;
constexpr int SS = 2048;
constexpr int DIN = 1024;
constexpr int HH = 16;
constexpr int DH = 64;
constexpr int NOUT = 4096;          // 4 * 1024 (Q|K|V|R)
constexpr int MROWS = BB * SS;      // 8192

typedef __attribute__((ext_vector_type(8))) short bf16x8;
typedef __attribute__((ext_vector_type(8))) unsigned short u16x8;
typedef __attribute__((ext_vector_type(4))) unsigned short u16x4;
typedef __attribute__((ext_vector_type(4))) float f32x4;

__device__ __forceinline__ unsigned short f2bf(float f) {
  unsigned int x = __float_as_uint(f);
  unsigned int r = (x + 0x7fffu + ((x >> 16) & 1u)) >> 16;
  return (unsigned short)r;
}
__device__ __forceinline__ float bf2f(unsigned short u) {
  return __uint_as_float(((unsigned int)u) << 16);
}

__device__ __forceinline__ void gload16(const void* g, void* l) {
  typedef __attribute__((address_space(1))) void gvoid;
  typedef __attribute__((address_space(3))) void lvoid;
  __builtin_amdgcn_global_load_lds((gvoid*)(uintptr_t)g, (lvoid*)l, 16, 0, 0);
}

// ---------------- fp32 -> bf16 conversions ----------------
__global__ __launch_bounds__(256) void convert_x(const float* __restrict__ src,
                                                 unsigned short* __restrict__ dst) {
  int i = (blockIdx.x * 256 + threadIdx.x) * 8;  // n = 8388608 exactly covered
  f32x4 a = *(const f32x4*)(src + i);
  f32x4 b = *(const f32x4*)(src + i + 4);
  u16x8 o;
  o[0] = f2bf(a[0]); o[1] = f2bf(a[1]); o[2] = f2bf(a[2]); o[3] = f2bf(a[3]);
  o[4] = f2bf(b[0]); o[5] = f2bf(b[1]); o[6] = f2bf(b[2]); o[7] = f2bf(b[3]);
  *(u16x8*)(dst + i) = o;
}

__global__ __launch_bounds__(256) void convert_w(const float* __restrict__ Wq,
                                                 const float* __restrict__ Wk,
                                                 const float* __restrict__ Wv,
                                                 const float* __restrict__ Wr,
                                                 unsigned short* __restrict__ dst) {
  int i = (blockIdx.x * 256 + threadIdx.x) * 8;   // 0 .. 4M
  int seg = i >> 20;                              // each W: 2^20 elems
  const float* src = (seg == 0) ? Wq : (seg == 1) ? Wk : (seg == 2) ? Wv : Wr;
  // fold 1/sqrt(64) AND log2(e) into Wq: scores come out in log2 domain
  float scale = (seg == 0) ? 0.125f * 1.44269504088896f : 1.0f;
  int j = i & 1048575;
  f32x4 a = *(const f32x4*)(src + j);
  f32x4 b = *(const f32x4*)(src + j + 4);
  u16x8 o;
  o[0] = f2bf(a[0] * scale); o[1] = f2bf(a[1] * scale);
  o[2] = f2bf(a[2] * scale); o[3] = f2bf(a[3] * scale);
  o[4] = f2bf(b[0] * scale); o[5] = f2bf(b[1] * scale);
  o[6] = f2bf(b[2] * scale); o[7] = f2bf(b[3] * scale);
  *(u16x8*)(dst + i) = o;
}

// ---------------- QKVR GEMM: Y[8192][4096] = X[8192][1024] @ W[4096][1024]^T ----------------
// 256x256 tile, BK=32, 3-BUFFER LDS ring (96 KB), 512 thr / 8 waves (2x4),
// per-wave C = 128x64 (8x4 frags). 2 phases per K-tile, each
// {ds_read subtile, 2 gload_lds, barrier, lgkmcnt(0), setprio 16xMFMA, barrier};
// vmcnt(4) ONCE per K-tile (never 0 in-loop): tile t+2 staged into the ring slot
// freed at iter t-1's closing barrier -> no read/write overlap by construction.
// LDS layout: 128B super-row = row-pair (2m x 32k); 8 16B-slots, slot = logical
// ((m&1)*4 + k16) ^ (sr&7) -> frag reads hit each bank-quad exactly 2x (free).
constexpr int GBM = 256, GBN = 256, GBK = 32;

__global__ __launch_bounds__(512) void gemm_qkvr(const unsigned short* __restrict__ X,
                                                 const unsigned short* __restrict__ Wt,
                                                 unsigned short* __restrict__ Y) {
  const int K = DIN;            // 1024, 32 K-tiles of 32
  // XCD-chunked bijective swizzle (512 % 8 == 0)
  int bid = blockIdx.x;
  int idx = (bid & 7) * 64 + (bid >> 3);
  int bm = idx >> 4, bn = idx & 15;     // 32 x 16 tiles
  int m0 = bm * GBM, n0 = bn * GBN;
  int t = threadIdx.x;
  int w = t >> 6, l = t & 63;
  int lg = l >> 4, ll = l & 15;
  int wr = w & 1, wc = w >> 1;          // wave grid 2(M) x 4(N)

  __shared__ unsigned short As[3][8192];  // 16 KB per buffer
  __shared__ unsigned short Bs[3][8192];

  f32x4 acc[8][4];
#pragma unroll
  for (int i = 0; i < 8; i++)
#pragma unroll
    for (int j = 0; j < 4; j++) acc[i][j] = (f32x4)0.0f;

  // frag-read addressing (per-lane constant): m = wr*128 + mt*16 + ll
  // super-row sr = m>>1; phys slot = ((m&1)*4 + lg) ^ (sr&7); elem = sr*64 + slot*8
  int qA = ((ll & 1) * 4 + lg) ^ ((ll >> 1) & 7);
  int aoff = (wr * 64 + (ll >> 1)) * 64 + qA * 8;   // + mt*512
  int boff = (wc * 32 + (ll >> 1)) * 64 + qA * 8;   // + nt*512

  // staging source mapping (inverse of the layout): thread t, chunk c:
  // sr = c*64 + (t>>3), phys p = t&7, q = p ^ (sr&7) -> m = 2sr + (q>>2), k16 = q&3
  int qs = (t & 7) ^ ((t >> 3) & 7);
  int mloc0 = ((t >> 3) << 1) + ((qs >> 2) & 1);    // + c*128
  int kloc = (qs & 3) * 8;

  auto stageA = [&](int kt, int bi) {
#pragma unroll
    for (int c = 0; c < 2; ++c)
      gload16(X + (size_t)(m0 + mloc0 + c * 128) * K + kt * GBK + kloc,
              &As[bi][c * 4096 + t * 8]);
  };
  auto stageB = [&](int kt, int bi) {
#pragma unroll
    for (int c = 0; c < 2; ++c)
      gload16(Wt + (size_t)(n0 + mloc0 + c * 128) * K + kt * GBK + kloc,
              &Bs[bi][c * 4096 + t * 8]);
  };

  // prologue: tiles 0,1 into buffers 0,1 (8 loads); retire tile 0, keep tile 1
  stageA(0, 0); stageB(0, 0);
  stageA(1, 1); stageB(1, 1);
  asm volatile("s_waitcnt vmcnt(4)" ::: "memory");
  __builtin_amdgcn_s_barrier();

  int cur = 0;
  for (int kt = 0; kt < 32; ++kt) {
    int nb2 = cur + 2; if (nb2 >= 3) nb2 -= 3;   // ring slot for tile kt+2 (freed @ iter kt-1)
    int ktp2 = (kt + 2) & 31;                    // tail wraps re-stage tiles 0,1 (dummy, uniform vmcnt)

    bf16x8 a[8], b[4];
    // ---- phase 0: m-frags 0-3 x all n ----
#pragma unroll
    for (int mt = 0; mt < 4; ++mt) a[mt] = *(const bf16x8*)&As[cur][aoff + mt * 512];
#pragma unroll
    for (int nt = 0; nt < 4; ++nt) b[nt] = *(const bf16x8*)&Bs[cur][boff + nt * 512];
    stageA(ktp2, nb2);
    __builtin_amdgcn_s_barrier();
    asm volatile("s_waitcnt lgkmcnt(0)" ::: "memory");
    __builtin_amdgcn_s_setprio(1);
#pragma unroll
    for (int mt = 0; mt < 4; ++mt)
#pragma unroll
      for (int nt = 0; nt < 4; ++nt)
        acc[mt][nt] = __builtin_amdgcn_mfma_f32_16x16x32_bf16(a[mt], b[nt], acc[mt][nt], 0, 0, 0);
    __builtin_amdgcn_s_setprio(0);
    __builtin_amdgcn_s_barrier();

    // ---- phase 1: m-frags 4-7 (B held in regs) ----
#pragma unroll
    for (int mt = 4; mt < 8; ++mt) a[mt] = *(const bf16x8*)&As[cur][aoff + mt * 512];
    stageB(ktp2, nb2);
    __builtin_amdgcn_s_barrier();
    asm volatile("s_waitcnt lgkmcnt(0)" ::: "memory");
    __builtin_amdgcn_s_setprio(1);
#pragma unroll
    for (int mt = 4; mt < 8; ++mt)
#pragma unroll
      for (int nt = 0; nt < 4; ++nt)
        acc[mt][nt] = __builtin_amdgcn_mfma_f32_16x16x32_bf16(a[mt], b[nt], acc[mt][nt], 0, 0, 0);
    __builtin_amdgcn_s_setprio(0);
    asm volatile("s_waitcnt vmcnt(4)" ::: "memory");  // retire tile kt+1; tile kt+2 stays in flight
    __builtin_amdgcn_s_barrier();

    cur += 1; if (cur == 3) cur = 0;
  }
  asm volatile("s_waitcnt vmcnt(0)" ::: "memory");  // drain tail dummy stages

  // epilogue: C/D mapping col = lane&15 (n), row = (lane>>4)*4 + r (m)
#pragma unroll
  for (int mt = 0; mt < 8; ++mt)
#pragma unroll
    for (int nt = 0; nt < 4; ++nt) {
      int n = n0 + wc * 64 + nt * 16 + ll;
#pragma unroll
      for (int r = 0; r < 4; ++r) {
        int m = m0 + wr * 128 + mt * 16 + lg * 4 + r;
        Y[(size_t)m * NOUT + n] = f2bf(acc[mt][nt][r]);
      }
    }
}

// ---------------- V transpose: (B,S,H,64) slice of qkvr -> Vt[(b*H+h)*64 + d][S] ----------------
__global__ __launch_bounds__(256) void transpose_v(const unsigned short* __restrict__ qkvr,
                                                   unsigned short* __restrict__ vt) {
  int bh = blockIdx.x >> 5;   // 0..63
  int st = blockIdx.x & 31;   // s-tile of 64
  int b = bh >> 4, h = bh & 15;
  __shared__ unsigned short tile[64][72];
  int t = threadIdx.x;
#pragma unroll
  for (int c = 0; c < 2; ++c) {
    int chunk = t + c * 256;
    int row = chunk >> 3;        // s 0..63
    int col = (chunk & 7) * 8;   // d
    u16x8 v = *(const u16x8*)(qkvr + (size_t)(b * SS + st * 64 + row) * NOUT + 2048 + h * DH + col);
    *(u16x8*)&tile[row][col] = v;
  }
  __syncthreads();
  int d = t >> 2;
  int s0 = (t & 3) * 16;
  u16x8 o0, o1;
#pragma unroll
  for (int i = 0; i < 8; ++i) o0[i] = tile[s0 + i][d];
#pragma unroll
  for (int i = 0; i < 8; ++i) o1[i] = tile[s0 + 8 + i][d];
  size_t orow = (size_t)(bh * DH + d) * SS + st * 64 + s0;
  *(u16x8*)(vt + orow) = o0;
  *(u16x8*)(vt + orow + 8) = o1;
}

// ---------------- Flash attention ----------------
// block: one (b,h), 256 q-rows; 8 waves x 32 rows. KV tiles of 64, double-buffered,
// counted vmcnt, XOR-swizzled K/V LDS. STATIC softmax (log2e folded into Wq).
// SWAPPED QK^T -> P lane-local per q-row; P via per-wave LDS P^T (b64 write / b128 read).
// DENOMINATOR VIA MFMA (B = ones): C layout matches the output store exactly.
__global__ __launch_bounds__(512) void attention(const unsigned short* __restrict__ qkvr,
                                                 const unsigned short* __restrict__ vt,
                                                 unsigned short* __restrict__ attn) {
  int bid = blockIdx.x;                    // 512 blocks
  int idx = (bid & 7) * 64 + (bid >> 3);   // XCD-chunked bijective swizzle
  int qt = idx & 7;
  int bh = idx >> 3;
  int b = bh >> 4, h = bh & 15;
  int t = threadIdx.x, w = t >> 6, l = t & 63;
  int lg = l >> 4, ll = l & 15;

  __shared__ unsigned short Ks[2][4096];   // [64 k][64 d] x2, swizzled (16 KB)
  __shared__ unsigned short Vs[2][4096];   // Vt tile [64 d][64 s] x2, swizzled (16 KB)
  __shared__ unsigned short Ps[8][2048];   // per-wave P^T [32 q][64 k], swizzled (32 KB)

  const unsigned short* kbase = qkvr + (size_t)(b * SS) * NOUT + 1024 + h * DH;
  const unsigned short* vbase = vt + (size_t)(bh * DH) * SS;

  // Q fragments (B-operand: col q = ll, mfma-k (d) = kk*32 + lg*8 + 0..7)
  bf16x8 qb[2][2];
#pragma unroll
  for (int m = 0; m < 2; ++m) {
    int qrow = b * SS + qt * 256 + w * 32 + m * 16 + ll;
#pragma unroll
    for (int kk = 0; kk < 2; ++kk)
      qb[m][kk] = *(const bf16x8*)(qkvr + (size_t)qrow * NOUT + h * DH + kk * 32 + lg * 8);
  }

  bf16x8 ones;
#pragma unroll
  for (int i = 0; i < 8; i++) ones[i] = (short)0x3F80;  // bf16 1.0

  f32x4 acc[2][4];
  f32x4 dacc[2];                 // denominator accumulator (mfma C layout)
#pragma unroll
  for (int m = 0; m < 2; ++m) {
    dacc[m] = (f32x4)0.0f;
#pragma unroll
    for (int i = 0; i < 4; i++) acc[m][i] = (f32x4)0.0f;
  }

  // staging (512 threads): lane t -> row = t>>3 (0..63), 16B slot = t&7,
  // pre-swizzled global col: slot ^ (row&7). LDS dest linear: wave base + lane*16.
  int grow = t >> 3;
  int gcol = ((t & 7) ^ (grow & 7)) * 8;

  auto stage = [&](int tile, int bi) {
    gload16(kbase + (size_t)(tile * 64 + grow) * NOUT + gcol, &Ks[bi][w * 512]);
    gload16(vbase + (size_t)grow * SS + tile * 64 + gcol, &Vs[bi][w * 512]);
  };

  stage(0, 0);

  for (int kt = 0; kt < 32; ++kt) {
    int bi = kt & 1;
    stage((kt + 1) & 31, bi ^ 1);  // kt=31 re-stages tile 0 (harmless) to keep vmcnt uniform
    asm volatile("s_waitcnt vmcnt(2)" ::: "memory");
    __builtin_amdgcn_s_barrier();
    __builtin_amdgcn_sched_barrier(0);

    // S'^T = K Q^T (log2 domain): s[m][nt][r] -> q = m*16+ll, k = nt*16+lg*4+r
    f32x4 s[2][4];
#pragma unroll
    for (int m = 0; m < 2; ++m)
#pragma unroll
      for (int nt = 0; nt < 4; nt++) s[m][nt] = (f32x4)0.0f;
    __builtin_amdgcn_s_setprio(1);
#pragma unroll
    for (int nt = 0; nt < 4; ++nt)
#pragma unroll
      for (int kk = 0; kk < 2; ++kk) {
        bf16x8 kb = *(const bf16x8*)&Ks[bi][(nt * 16 + ll) * 64 + ((kk * 4 + lg) ^ (ll & 7)) * 8];
        s[0][nt] = __builtin_amdgcn_mfma_f32_16x16x32_bf16(kb, qb[0][kk], s[0][nt], 0, 0, 0);
        s[1][nt] = __builtin_amdgcn_mfma_f32_16x16x32_bf16(kb, qb[1][kk], s[1][nt], 0, 0, 0);
      }
    __builtin_amdgcn_s_setprio(0);

    // P = exp2(S') (no max, no rescale, no VALU sum — denom comes from MFMA below)
#pragma unroll
    for (int m = 0; m < 2; ++m)
#pragma unroll
      for (int nt = 0; nt < 4; nt++)
#pragma unroll
        for (int r = 0; r < 4; r++) {
          float e;
          asm("v_exp_f32 %0, %1" : "=v"(e) : "v"(s[m][nt][r]));
          s[m][nt][r] = e;
        }

    // pack 4 consecutive k (nt*16+lg*4+0..3) -> b64 store into P^T row q=m*16+ll.
    // swizzle: 16B-slot (2nt + (lg>>1)) ^ (row&7), row&7 == ll&7; 8B half = lg&1.
#pragma unroll
    for (int m = 0; m < 2; ++m) {
      char* prow = (char*)&Ps[w][0] + (m * 16 + ll) * 128;
#pragma unroll
      for (int nt = 0; nt < 4; nt++) {
        unsigned sp0, sp1;
        asm("v_cvt_pk_bf16_f32 %0, %1, %2" : "=v"(sp0) : "v"(s[m][nt][0]), "v"(s[m][nt][1]));
        asm("v_cvt_pk_bf16_f32 %0, %1, %2" : "=v"(sp1) : "v"(s[m][nt][2]), "v"(s[m][nt][3]));
        uint2 pv; pv.x = sp0; pv.y = sp1;
        *(uint2*)(prow + ((2 * nt + (lg >> 1)) ^ (ll & 7)) * 16 + (lg & 1) * 8) = pv;
      }
    }

    // PV A-frags: row q = m*16+ll, k = kk*32+lg*8+0..7 -> slot (4kk+lg)^(ll&7)
    bf16x8 pa[2][2];
#pragma unroll
    for (int m = 0; m < 2; ++m)
#pragma unroll
      for (int kk = 0; kk < 2; ++kk)
        pa[m][kk] = *(const bf16x8*)((char*)&Ps[w][0] + (m * 16 + ll) * 128 +
                                     ((4 * kk + lg) ^ (ll & 7)) * 16);

    // PV: A = P (row=q), B = Vt tile [d][k] (k-contiguous); + denominator mfma (B=ones)
    __builtin_amdgcn_s_setprio(1);
#pragma unroll
    for (int kk = 0; kk < 2; ++kk) {
#pragma unroll
      for (int dt = 0; dt < 4; ++dt) {
        bf16x8 vb = *(const bf16x8*)&Vs[bi][(dt * 16 + ll) * 64 + ((kk * 4 + lg) ^ (ll & 7)) * 8];
        acc[0][dt] = __builtin_amdgcn_mfma_f32_16x16x32_bf16(pa[0][kk], vb, acc[0][dt], 0, 0, 0);
        acc[1][dt] = __builtin_amdgcn_mfma_f32_16x16x32_bf16(pa[1][kk], vb, acc[1][dt], 0, 0, 0);
      }
      dacc[0] = __builtin_amdgcn_mfma_f32_16x16x32_bf16(pa[0][kk], ones, dacc[0], 0, 0, 0);
      dacc[1] = __builtin_amdgcn_mfma_f32_16x16x32_bf16(pa[1][kk], ones, dacc[1], 0, 0, 0);
    }
    __builtin_amdgcn_s_setprio(0);
    __builtin_amdgcn_s_barrier();
    __builtin_amdgcn_sched_barrier(0);
  }
  asm volatile("s_waitcnt vmcnt(0)" ::: "memory");  // drain dummy stage before endpgm

  // output: acc[m][dt][r] -> q = m*16 + lg*4 + r, d = dt*16 + ll.
  // dacc[m][r] holds the full denominator for exactly that q — no shuffles needed.
#pragma unroll
  for (int m = 0; m < 2; ++m)
#pragma unroll
    for (int r = 0; r < 4; r++) {
      float inv = 1.0f / dacc[m][r];
      int arow = b * SS + qt * 256 + w * 32 + m * 16 + lg * 4 + r;
#pragma unroll
      for (int dt = 0; dt < 4; dt++)
        attn[(size_t)arow * DIN + h * DH + dt * 16 + ll] = f2bf(acc[m][dt][r] * inv);
    }
}

// ---------------- LayerNorm epilogue: out = LN(relu(attn + R)) ----------------
__global__ __launch_bounds__(256) void ln_epilogue(const unsigned short* __restrict__ attn,
                                                   const unsigned short* __restrict__ qkvr,
                                                   const float* __restrict__ gamma,
                                                   const float* __restrict__ beta,
                                                   float* __restrict__ out) {
  int row = blockIdx.x;
  int t = threadIdx.x;
  u16x4 av = *(const u16x4*)(attn + (size_t)row * DIN + t * 4);
  u16x4 rv = *(const u16x4*)(qkvr + (size_t)row * NOUT + 3072 + t * 4);
  float v[4];
  float s = 0.0f, s2 = 0.0f;
#pragma unroll
  for (int i = 0; i < 4; i++) {
    v[i] = fmaxf(bf2f(av[i]) + bf2f(rv[i]), 0.0f);
    s += v[i];
    s2 += v[i] * v[i];
  }
#pragma unroll
  for (int m = 1; m < 64; m <<= 1) {
    s += __shfl_xor(s, m);
    s2 += __shfl_xor(s2, m);
  }
  __shared__ float red[2][4];
  int w = t >> 6, l = t & 63;
  if (l == 0) { red[0][w] = s; red[1][w] = s2; }
  __syncthreads();
  s = red[0][0] + red[0][1] + red[0][2] + red[0][3];
  s2 = red[1][0] + red[1][1] + red[1][2] + red[1][3];
  float mu = s * (1.0f / 1024.0f);
  float var = s2 * (1.0f / 1024.0f) - mu * mu;
  float rstd = rsqrtf(var + 1e-5f);
  f32x4 g = *(const f32x4*)(gamma + t * 4);
  f32x4 be = *(const f32x4*)(beta + t * 4);
  f32x4 o;
#pragma unroll
  for (int i = 0; i < 4; i++) o[i] = (v[i] - mu) * rstd * g[i] + be[i];
  *(f32x4*)(out + (size_t)row * DIN + t * 4) = o;
}

extern "C" void kernel_launch(void* const* d_in, const int* in_sizes, int n_in,
                              void* d_out, int out_size, void* d_ws, size_t ws_size,
                              hipStream_t stream) {
  const float* x = (const float*)d_in[0];
  const float* Wq = (const float*)d_in[1];
  const float* Wk = (const float*)d_in[2];
  const float* Wv = (const float*)d_in[3];
  const float* Wr = (const float*)d_in[4];
  const float* gamma = (const float*)d_in[5];
  const float* beta = (const float*)d_in[6];
  float* out = (float*)d_out;

  char* ws = (char*)d_ws;
  unsigned short* x_bf = (unsigned short*)ws;                        // 16 MB
  unsigned short* w_bf = (unsigned short*)(ws + (16ull << 20));      // 8 MB
  unsigned short* qkvr = (unsigned short*)(ws + (24ull << 20));      // 64 MB
  unsigned short* vt   = (unsigned short*)(ws + (88ull << 20));      // 16 MB
  unsigned short* attn = (unsigned short*)(ws + (104ull << 20));     // 16 MB (total 120 MB)

  convert_x<<<4096, 256, 0, stream>>>(x, x_bf);
  convert_w<<<2048, 256, 0, stream>>>(Wq, Wk, Wv, Wr, w_bf);
  gemm_qkvr<<<(MROWS / GBM) * (NOUT / GBN), 512, 0, stream>>>(x_bf, w_bf, qkvr);
  transpose_v<<<2048, 256, 0, stream>>>(qkvr, vt);
  attention<<<512, 512, 0, stream>>>(qkvr, vt, attn);
  ln_epilogue<<<MROWS, 256, 0, stream>>>(attn, qkvr, gamma, beta, out);
}

// Round 16
// 177.504 us; speedup vs baseline: 1.1232x; 1.0376x over previous
//
#include <hip/hip_runtime.h>
#include <hip/hip_bf16.h>
#include <stdint.h>

// Problem constants
constexpr int BB = 4;
constexpr int SS = 2048;
constexpr int DIN = 1024;
constexpr int HH = 16;
constexpr int DH = 64;
constexpr int NOUT = 4096;          // 4 * 1024 (Q|K|V|R)
constexpr int MROWS = BB * SS;      // 8192

typedef __attribute__((ext_vector_type(8))) short bf16x8;
typedef __attribute__((ext_vector_type(8))) unsigned short u16x8;
typedef __attribute__((ext_vector_type(4))) unsigned short u16x4;
typedef __attribute__((ext_vector_type(4))) float f32x4;

__device__ __forceinline__ unsigned short f2bf(float f) {
  unsigned int x = __float_as_uint(f);
  unsigned int r = (x + 0x7fffu + ((x >> 16) & 1u)) >> 16;
  return (unsigned short)r;
}
__device__ __forceinline__ float bf2f(unsigned short u) {
  return __uint_as_float(((unsigned int)u) << 16);
}

__device__ __forceinline__ void gload16(const void* g, void* l) {
  typedef __attribute__((address_space(1))) void gvoid;
  typedef __attribute__((address_space(3))) void lvoid;
  __builtin_amdgcn_global_load_lds((gvoid*)(uintptr_t)g, (lvoid*)l, 16, 0, 0);
}

// ---------------- fp32 -> bf16 conversions ----------------
__global__ __launch_bounds__(256) void convert_x(const float* __restrict__ src,
                                                 unsigned short* __restrict__ dst) {
  int i = (blockIdx.x * 256 + threadIdx.x) * 8;  // n = 8388608 exactly covered
  f32x4 a = *(const f32x4*)(src + i);
  f32x4 b = *(const f32x4*)(src + i + 4);
  u16x8 o;
  o[0] = f2bf(a[0]); o[1] = f2bf(a[1]); o[2] = f2bf(a[2]); o[3] = f2bf(a[3]);
  o[4] = f2bf(b[0]); o[5] = f2bf(b[1]); o[6] = f2bf(b[2]); o[7] = f2bf(b[3]);
  *(u16x8*)(dst + i) = o;
}

__global__ __launch_bounds__(256) void convert_w(const float* __restrict__ Wq,
                                                 const float* __restrict__ Wk,
                                                 const float* __restrict__ Wv,
                                                 const float* __restrict__ Wr,
                                                 unsigned short* __restrict__ dst) {
  int i = (blockIdx.x * 256 + threadIdx.x) * 8;   // 0 .. 4M
  int seg = i >> 20;                              // each W: 2^20 elems
  const float* src = (seg == 0) ? Wq : (seg == 1) ? Wk : (seg == 2) ? Wv : Wr;
  // fold 1/sqrt(64) AND log2(e) into Wq: scores come out in log2 domain
  float scale = (seg == 0) ? 0.125f * 1.44269504088896f : 1.0f;
  int j = i & 1048575;
  f32x4 a = *(const f32x4*)(src + j);
  f32x4 b = *(const f32x4*)(src + j + 4);
  u16x8 o;
  o[0] = f2bf(a[0] * scale); o[1] = f2bf(a[1] * scale);
  o[2] = f2bf(a[2] * scale); o[3] = f2bf(a[3] * scale);
  o[4] = f2bf(b[0] * scale); o[5] = f2bf(b[1] * scale);
  o[6] = f2bf(b[2] * scale); o[7] = f2bf(b[3] * scale);
  *(u16x8*)(dst + i) = o;
}

// ---------------- QKVR GEMM: Y[8192][4096] = X[8192][1024] @ W[4096][1024]^T ----------------
// 256x256 tile, BK=32, 3-BUFFER LDS ring (96 KB), 512 thr / 8 waves (2x4),
// per-wave C = 128x64 (8x4 frags). 2 phases per K-tile; vmcnt(4) once per K-tile.
// V-FUSION: tiles with bn in [8,12) (the V segment of Q|K|V|R) store their output
// DIRECTLY in transposed Vt layout vt[(b*16+h)*64 + d][s] (8B packed stores),
// skipping the Y write entirely -> transpose_v kernel eliminated.
constexpr int GBM = 256, GBN = 256, GBK = 32;

__global__ __launch_bounds__(512) void gemm_qkvr(const unsigned short* __restrict__ X,
                                                 const unsigned short* __restrict__ Wt,
                                                 unsigned short* __restrict__ Y,
                                                 unsigned short* __restrict__ vt) {
  const int K = DIN;            // 1024, 32 K-tiles of 32
  int bid = blockIdx.x;
  int idx = (bid & 7) * 64 + (bid >> 3);
  int bm = idx >> 4, bn = idx & 15;     // 32 x 16 tiles
  int m0 = bm * GBM, n0 = bn * GBN;
  int t = threadIdx.x;
  int w = t >> 6, l = t & 63;
  int lg = l >> 4, ll = l & 15;
  int wr = w & 1, wc = w >> 1;          // wave grid 2(M) x 4(N)

  __shared__ unsigned short As[3][8192];  // 16 KB per buffer
  __shared__ unsigned short Bs[3][8192];

  f32x4 acc[8][4];
#pragma unroll
  for (int i = 0; i < 8; i++)
#pragma unroll
    for (int j = 0; j < 4; j++) acc[i][j] = (f32x4)0.0f;

  int qA = ((ll & 1) * 4 + lg) ^ ((ll >> 1) & 7);
  int aoff = (wr * 64 + (ll >> 1)) * 64 + qA * 8;   // + mt*512
  int boff = (wc * 32 + (ll >> 1)) * 64 + qA * 8;   // + nt*512

  int qs = (t & 7) ^ ((t >> 3) & 7);
  int mloc0 = ((t >> 3) << 1) + ((qs >> 2) & 1);    // + c*128
  int kloc = (qs & 3) * 8;

  auto stageA = [&](int kt, int bi) {
#pragma unroll
    for (int c = 0; c < 2; ++c)
      gload16(X + (size_t)(m0 + mloc0 + c * 128) * K + kt * GBK + kloc,
              &As[bi][c * 4096 + t * 8]);
  };
  auto stageB = [&](int kt, int bi) {
#pragma unroll
    for (int c = 0; c < 2; ++c)
      gload16(Wt + (size_t)(n0 + mloc0 + c * 128) * K + kt * GBK + kloc,
              &Bs[bi][c * 4096 + t * 8]);
  };

  stageA(0, 0); stageB(0, 0);
  stageA(1, 1); stageB(1, 1);
  asm volatile("s_waitcnt vmcnt(4)" ::: "memory");
  __builtin_amdgcn_s_barrier();

  int cur = 0;
  for (int kt = 0; kt < 32; ++kt) {
    int nb2 = cur + 2; if (nb2 >= 3) nb2 -= 3;
    int ktp2 = (kt + 2) & 31;

    bf16x8 a[8], b[4];
    // ---- phase 0 ----
#pragma unroll
    for (int mt = 0; mt < 4; ++mt) a[mt] = *(const bf16x8*)&As[cur][aoff + mt * 512];
#pragma unroll
    for (int nt = 0; nt < 4; ++nt) b[nt] = *(const bf16x8*)&Bs[cur][boff + nt * 512];
    stageA(ktp2, nb2);
    __builtin_amdgcn_s_barrier();
    asm volatile("s_waitcnt lgkmcnt(0)" ::: "memory");
    __builtin_amdgcn_s_setprio(1);
#pragma unroll
    for (int mt = 0; mt < 4; ++mt)
#pragma unroll
      for (int nt = 0; nt < 4; ++nt)
        acc[mt][nt] = __builtin_amdgcn_mfma_f32_16x16x32_bf16(a[mt], b[nt], acc[mt][nt], 0, 0, 0);
    __builtin_amdgcn_s_setprio(0);
    __builtin_amdgcn_s_barrier();

    // ---- phase 1 ----
#pragma unroll
    for (int mt = 4; mt < 8; ++mt) a[mt] = *(const bf16x8*)&As[cur][aoff + mt * 512];
    stageB(ktp2, nb2);
    __builtin_amdgcn_s_barrier();
    asm volatile("s_waitcnt lgkmcnt(0)" ::: "memory");
    __builtin_amdgcn_s_setprio(1);
#pragma unroll
    for (int mt = 4; mt < 8; ++mt)
#pragma unroll
      for (int nt = 0; nt < 4; ++nt)
        acc[mt][nt] = __builtin_amdgcn_mfma_f32_16x16x32_bf16(a[mt], b[nt], acc[mt][nt], 0, 0, 0);
    __builtin_amdgcn_s_setprio(0);
    asm volatile("s_waitcnt vmcnt(4)" ::: "memory");
    __builtin_amdgcn_s_barrier();

    cur += 1; if (cur == 3) cur = 0;
  }
  asm volatile("s_waitcnt vmcnt(0)" ::: "memory");

  if (bn >= 8 && bn < 12) {
    // V segment: store transposed to vt[(b*16 + h)*64 + d][s]; no Y write.
    // n = n0 + wc*64 + nt*16 + ll -> h = (bn-8)*4 + wc, d = nt*16 + ll (<64).
    int hh = (bn - 8) * 4 + wc;
    int b = m0 >> 11;                       // batch constant per block (m-range 256)
#pragma unroll
    for (int mt = 0; mt < 8; ++mt) {
      int s = (m0 & 2047) + wr * 128 + mt * 16 + lg * 4;
#pragma unroll
      for (int nt = 0; nt < 4; ++nt) {
        int d = nt * 16 + ll;
        u16x4 o;
#pragma unroll
        for (int r = 0; r < 4; ++r) o[r] = f2bf(acc[mt][nt][r]);
        *(u16x4*)(vt + (size_t)((b * 16 + hh) * 64 + d) * SS + s) = o;
      }
    }
  } else {
    // epilogue: C/D mapping col = lane&15 (n), row = (lane>>4)*4 + r (m)
#pragma unroll
    for (int mt = 0; mt < 8; ++mt)
#pragma unroll
      for (int nt = 0; nt < 4; ++nt) {
        int n = n0 + wc * 64 + nt * 16 + ll;
#pragma unroll
        for (int r = 0; r < 4; ++r) {
          int m = m0 + wr * 128 + mt * 16 + lg * 4 + r;
          Y[(size_t)m * NOUT + n] = f2bf(acc[mt][nt][r]);
        }
      }
  }
}

// ---------------- Flash attention ----------------
// block: one (b,h), 256 q-rows; 8 waves x 32 rows. KV tiles of 64, double-buffered,
// counted vmcnt, XOR-swizzled K/V LDS. STATIC softmax (log2e folded into Wq).
// SWAPPED QK^T -> P lane-local per q-row; P via per-wave LDS P^T (b64 write / b128 read).
// DENOMINATOR VIA MFMA (B = ones): C layout matches the output store exactly.
__global__ __launch_bounds__(512) void attention(const unsigned short* __restrict__ qkvr,
                                                 const unsigned short* __restrict__ vt,
                                                 unsigned short* __restrict__ attn) {
  int bid = blockIdx.x;                    // 512 blocks
  int idx = (bid & 7) * 64 + (bid >> 3);   // XCD-chunked bijective swizzle
  int qt = idx & 7;
  int bh = idx >> 3;
  int b = bh >> 4, h = bh & 15;
  int t = threadIdx.x, w = t >> 6, l = t & 63;
  int lg = l >> 4, ll = l & 15;

  __shared__ unsigned short Ks[2][4096];   // [64 k][64 d] x2, swizzled (16 KB)
  __shared__ unsigned short Vs[2][4096];   // Vt tile [64 d][64 s] x2, swizzled (16 KB)
  __shared__ unsigned short Ps[8][2048];   // per-wave P^T [32 q][64 k], swizzled (32 KB)

  const unsigned short* kbase = qkvr + (size_t)(b * SS) * NOUT + 1024 + h * DH;
  const unsigned short* vbase = vt + (size_t)(bh * DH) * SS;

  // Q fragments (B-operand: col q = ll, mfma-k (d) = kk*32 + lg*8 + 0..7)
  bf16x8 qb[2][2];
#pragma unroll
  for (int m = 0; m < 2; ++m) {
    int qrow = b * SS + qt * 256 + w * 32 + m * 16 + ll;
#pragma unroll
    for (int kk = 0; kk < 2; ++kk)
      qb[m][kk] = *(const bf16x8*)(qkvr + (size_t)qrow * NOUT + h * DH + kk * 32 + lg * 8);
  }

  bf16x8 ones;
#pragma unroll
  for (int i = 0; i < 8; i++) ones[i] = (short)0x3F80;  // bf16 1.0

  f32x4 acc[2][4];
  f32x4 dacc[2];                 // denominator accumulator (mfma C layout)
#pragma unroll
  for (int m = 0; m < 2; ++m) {
    dacc[m] = (f32x4)0.0f;
#pragma unroll
    for (int i = 0; i < 4; i++) acc[m][i] = (f32x4)0.0f;
  }

  // staging (512 threads): lane t -> row = t>>3 (0..63), 16B slot = t&7,
  // pre-swizzled global col: slot ^ (row&7). LDS dest linear: wave base + lane*16.
  int grow = t >> 3;
  int gcol = ((t & 7) ^ (grow & 7)) * 8;

  auto stage = [&](int tile, int bi) {
    gload16(kbase + (size_t)(tile * 64 + grow) * NOUT + gcol, &Ks[bi][w * 512]);
    gload16(vbase + (size_t)grow * SS + tile * 64 + gcol, &Vs[bi][w * 512]);
  };

  stage(0, 0);

  for (int kt = 0; kt < 32; ++kt) {
    int bi = kt & 1;
    stage((kt + 1) & 31, bi ^ 1);  // kt=31 re-stages tile 0 (harmless) to keep vmcnt uniform
    asm volatile("s_waitcnt vmcnt(2)" ::: "memory");
    __builtin_amdgcn_s_barrier();
    __builtin_amdgcn_sched_barrier(0);

    // S'^T = K Q^T (log2 domain): s[m][nt][r] -> q = m*16+ll, k = nt*16+lg*4+r
    f32x4 s[2][4];
#pragma unroll
    for (int m = 0; m < 2; ++m)
#pragma unroll
      for (int nt = 0; nt < 4; nt++) s[m][nt] = (f32x4)0.0f;
    __builtin_amdgcn_s_setprio(1);
#pragma unroll
    for (int nt = 0; nt < 4; ++nt)
#pragma unroll
      for (int kk = 0; kk < 2; ++kk) {
        bf16x8 kb = *(const bf16x8*)&Ks[bi][(nt * 16 + ll) * 64 + ((kk * 4 + lg) ^ (ll & 7)) * 8];
        s[0][nt] = __builtin_amdgcn_mfma_f32_16x16x32_bf16(kb, qb[0][kk], s[0][nt], 0, 0, 0);
        s[1][nt] = __builtin_amdgcn_mfma_f32_16x16x32_bf16(kb, qb[1][kk], s[1][nt], 0, 0, 0);
      }
    __builtin_amdgcn_s_setprio(0);

    // P = exp2(S') (no max, no rescale, no VALU sum — denom comes from MFMA below)
#pragma unroll
    for (int m = 0; m < 2; ++m)
#pragma unroll
      for (int nt = 0; nt < 4; nt++)
#pragma unroll
        for (int r = 0; r < 4; r++) {
          float e;
          asm("v_exp_f32 %0, %1" : "=v"(e) : "v"(s[m][nt][r]));
          s[m][nt][r] = e;
        }

    // pack 4 consecutive k (nt*16+lg*4+0..3) -> b64 store into P^T row q=m*16+ll.
    // swizzle: 16B-slot (2nt + (lg>>1)) ^ (row&7), row&7 == ll&7; 8B half = lg&1.
#pragma unroll
    for (int m = 0; m < 2; ++m) {
      char* prow = (char*)&Ps[w][0] + (m * 16 + ll) * 128;
#pragma unroll
      for (int nt = 0; nt < 4; nt++) {
        unsigned sp0, sp1;
        asm("v_cvt_pk_bf16_f32 %0, %1, %2" : "=v"(sp0) : "v"(s[m][nt][0]), "v"(s[m][nt][1]));
        asm("v_cvt_pk_bf16_f32 %0, %1, %2" : "=v"(sp1) : "v"(s[m][nt][2]), "v"(s[m][nt][3]));
        uint2 pv; pv.x = sp0; pv.y = sp1;
        *(uint2*)(prow + ((2 * nt + (lg >> 1)) ^ (ll & 7)) * 16 + (lg & 1) * 8) = pv;
      }
    }

    // PV A-frags: row q = m*16+ll, k = kk*32+lg*8+0..7 -> slot (4kk+lg)^(ll&7)
    bf16x8 pa[2][2];
#pragma unroll
    for (int m = 0; m < 2; ++m)
#pragma unroll
      for (int kk = 0; kk < 2; ++kk)
        pa[m][kk] = *(const bf16x8*)((char*)&Ps[w][0] + (m * 16 + ll) * 128 +
                                     ((4 * kk + lg) ^ (ll & 7)) * 16);

    // PV: A = P (row=q), B = Vt tile [d][k] (k-contiguous); + denominator mfma (B=ones)
    __builtin_amdgcn_s_setprio(1);
#pragma unroll
    for (int kk = 0; kk < 2; ++kk) {
#pragma unroll
      for (int dt = 0; dt < 4; ++dt) {
        bf16x8 vb = *(const bf16x8*)&Vs[bi][(dt * 16 + ll) * 64 + ((kk * 4 + lg) ^ (ll & 7)) * 8];
        acc[0][dt] = __builtin_amdgcn_mfma_f32_16x16x32_bf16(pa[0][kk], vb, acc[0][dt], 0, 0, 0);
        acc[1][dt] = __builtin_amdgcn_mfma_f32_16x16x32_bf16(pa[1][kk], vb, acc[1][dt], 0, 0, 0);
      }
      dacc[0] = __builtin_amdgcn_mfma_f32_16x16x32_bf16(pa[0][kk], ones, dacc[0], 0, 0, 0);
      dacc[1] = __builtin_amdgcn_mfma_f32_16x16x32_bf16(pa[1][kk], ones, dacc[1], 0, 0, 0);
    }
    __builtin_amdgcn_s_setprio(0);
    __builtin_amdgcn_s_barrier();
    __builtin_amdgcn_sched_barrier(0);
  }
  asm volatile("s_waitcnt vmcnt(0)" ::: "memory");  // drain dummy stage before endpgm

  // output: acc[m][dt][r] -> q = m*16 + lg*4 + r, d = dt*16 + ll.
  // dacc[m][r] holds the full denominator for exactly that q — no shuffles needed.
#pragma unroll
  for (int m = 0; m < 2; ++m)
#pragma unroll
    for (int r = 0; r < 4; r++) {
      float inv = 1.0f / dacc[m][r];
      int arow = b * SS + qt * 256 + w * 32 + m * 16 + lg * 4 + r;
#pragma unroll
      for (int dt = 0; dt < 4; dt++)
        attn[(size_t)arow * DIN + h * DH + dt * 16 + ll] = f2bf(acc[m][dt][r] * inv);
    }
}

// ---------------- LayerNorm epilogue: out = LN(relu(attn + R)) ----------------
__global__ __launch_bounds__(256) void ln_epilogue(const unsigned short* __restrict__ attn,
                                                   const unsigned short* __restrict__ qkvr,
                                                   const float* __restrict__ gamma,
                                                   const float* __restrict__ beta,
                                                   float* __restrict__ out) {
  int row = blockIdx.x;
  int t = threadIdx.x;
  u16x4 av = *(const u16x4*)(attn + (size_t)row * DIN + t * 4);
  u16x4 rv = *(const u16x4*)(qkvr + (size_t)row * NOUT + 3072 + t * 4);
  float v[4];
  float s = 0.0f, s2 = 0.0f;
#pragma unroll
  for (int i = 0; i < 4; i++) {
    v[i] = fmaxf(bf2f(av[i]) + bf2f(rv[i]), 0.0f);
    s += v[i];
    s2 += v[i] * v[i];
  }
#pragma unroll
  for (int m = 1; m < 64; m <<= 1) {
    s += __shfl_xor(s, m);
    s2 += __shfl_xor(s2, m);
  }
  __shared__ float red[2][4];
  int w = t >> 6, l = t & 63;
  if (l == 0) { red[0][w] = s; red[1][w] = s2; }
  __syncthreads();
  s = red[0][0] + red[0][1] + red[0][2] + red[0][3];
  s2 = red[1][0] + red[1][1] + red[1][2] + red[1][3];
  float mu = s * (1.0f / 1024.0f);
  float var = s2 * (1.0f / 1024.0f) - mu * mu;
  float rstd = rsqrtf(var + 1e-5f);
  f32x4 g = *(const f32x4*)(gamma + t * 4);
  f32x4 be = *(const f32x4*)(beta + t * 4);
  f32x4 o;
#pragma unroll
  for (int i = 0; i < 4; i++) o[i] = (v[i] - mu) * rstd * g[i] + be[i];
  *(f32x4*)(out + (size_t)row * DIN + t * 4) = o;
}

extern "C" void kernel_launch(void* const* d_in, const int* in_sizes, int n_in,
                              void* d_out, int out_size, void* d_ws, size_t ws_size,
                              hipStream_t stream) {
  const float* x = (const float*)d_in[0];
  const float* Wq = (const float*)d_in[1];
  const float* Wk = (const float*)d_in[2];
  const float* Wv = (const float*)d_in[3];
  const float* Wr = (const float*)d_in[4];
  const float* gamma = (const float*)d_in[5];
  const float* beta = (const float*)d_in[6];
  float* out = (float*)d_out;

  char* ws = (char*)d_ws;
  unsigned short* x_bf = (unsigned short*)ws;                        // 16 MB
  unsigned short* w_bf = (unsigned short*)(ws + (16ull << 20));      // 8 MB
  unsigned short* qkvr = (unsigned short*)(ws + (24ull << 20));      // 64 MB
  unsigned short* vt   = (unsigned short*)(ws + (88ull << 20));      // 16 MB
  unsigned short* attn = (unsigned short*)(ws + (104ull << 20));     // 16 MB (total 120 MB)

  convert_x<<<4096, 256, 0, stream>>>(x, x_bf);
  convert_w<<<2048, 256, 0, stream>>>(Wq, Wk, Wv, Wr, w_bf);
  gemm_qkvr<<<(MROWS / GBM) * (NOUT / GBN), 512, 0, stream>>>(x_bf, w_bf, qkvr, vt);
  attention<<<512, 512, 0, stream>>>(qkvr, vt, attn);
  ln_epilogue<<<MROWS, 256, 0, stream>>>(attn, qkvr, gamma, beta, out);
}